// Round 10
// baseline (278.486 us; speedup 1.0000x reference)
//
#include <hip/hip_runtime.h>

typedef _Float16 half2v __attribute__((ext_vector_type(2)));
typedef _Float16 half4 __attribute__((ext_vector_type(4)));
typedef _Float16 half8 __attribute__((ext_vector_type(8)));
typedef float floatx4 __attribute__((ext_vector_type(4)));

#define B_   8
#define SE   4096
#define SD   4096
#define D_   128
#define NT   64      // K/V rows per tile (verified image geometry)
#define LDB  136
#define LOG2E 1.44269504f

// async 16B global->LDS: per-lane global address, wave-uniform LDS base (+lane*16 by HW)
__device__ __forceinline__ void cp16_async(const _Float16* g, _Float16* l) {
    __builtin_amdgcn_global_load_lds((const __attribute__((address_space(1))) unsigned int*)g,
                                     (__attribute__((address_space(3))) unsigned int*)l, 16, 0, 0);
}

// ---------- prep 0: W16 = fp16(W), Wlo = fp16(W - W16)  (error split) ----------
__global__ __launch_bounds__(256) void wprep(const float* __restrict__ W,
                                             _Float16* __restrict__ W16,
                                             _Float16* __restrict__ Wlo) {
    int i = blockIdx.x * 256 + threadIdx.x;   // grid 64 -> 16384
    float w = W[i];
    _Float16 hi = (_Float16)w;
    W16[i] = hi;
    Wlo[i] = (_Float16)(w - (float)hi);
}

// ---------- prep 1: k' = fp16(b @ W^T) (error-split MFMA), vT = fp16(b^T) ----------
__global__ __launch_bounds__(256) void kvprep(const float* __restrict__ b,
                                              const _Float16* __restrict__ W16,
                                              const _Float16* __restrict__ Wlo,
                                              _Float16* __restrict__ kp,
                                              _Float16* __restrict__ vT) {
    __shared__ _Float16 bs[64 * LDB];   // 17408 B (reused for k' staging)
    const int bb = blockIdx.y, s0 = blockIdx.x * 64;
    const int tid = threadIdx.x, wave = tid >> 6, lane = tid & 63;
    const int l15 = lane & 15, quad = lane >> 4;

    // phase 1: stage fp16(b tile)
    const float* bg = b + ((size_t)bb * SE + s0) * D_;
    #pragma unroll
    for (int it = 0; it < 4; ++it) {
        int idx = tid + it * 256;
        int row = idx >> 4, seg = idx & 15;
        const float* src = bg + row * D_ + seg * 8;
        float4 a = *(const float4*)src;
        float4 c = *(const float4*)(src + 4);
        half8 hv;
        hv[0] = (_Float16)a.x; hv[1] = (_Float16)a.y; hv[2] = (_Float16)a.z; hv[3] = (_Float16)a.w;
        hv[4] = (_Float16)c.x; hv[5] = (_Float16)c.y; hv[6] = (_Float16)c.z; hv[7] = (_Float16)c.w;
        *(half8*)(bs + row * LDB + seg * 8) = hv;
    }
    __syncthreads();

    // phase 2: k'[s][d] = sum_e b[s][e] W[d][e]
    half8 af[4];
    #pragma unroll
    for (int ks = 0; ks < 4; ++ks)
        af[ks] = *(const half8*)(bs + (wave * 16 + l15) * LDB + ks * 32 + quad * 8);
    floatx4 acc[8];
    #pragma unroll
    for (int nt = 0; nt < 8; ++nt) acc[nt] = (floatx4){0.f, 0.f, 0.f, 0.f};
    #pragma unroll
    for (int ks = 0; ks < 4; ++ks) {
        #pragma unroll
        for (int nt = 0; nt < 8; ++nt) {
            half8 bh = *(const half8*)(W16 + (size_t)(nt * 16 + l15) * 128 + ks * 32 + quad * 8);
            half8 bl = *(const half8*)(Wlo + (size_t)(nt * 16 + l15) * 128 + ks * 32 + quad * 8);
            acc[nt] = __builtin_amdgcn_mfma_f32_16x16x32_f16(af[ks], bh, acc[nt], 0, 0, 0);
            acc[nt] = __builtin_amdgcn_mfma_f32_16x16x32_f16(af[ks], bl, acc[nt], 0, 0, 0);
        }
    }

    // phase 3: vT = fp16(b^T): all 256 threads, 4s x 8d micro-transpose each
    {
        const int sq = tid & 15, dg = tid >> 4;   // s = sq*4 .. +3, d = dg*8 .. +7
        half8 rowv[4];
        #pragma unroll
        for (int j = 0; j < 4; ++j)
            rowv[j] = *(const half8*)(bs + (sq * 4 + j) * LDB + dg * 8);
        #pragma unroll
        for (int r = 0; r < 8; ++r) {
            int d = dg * 8 + r;
            half4 o;
            #pragma unroll
            for (int j = 0; j < 4; ++j) o[j] = rowv[j][r];
            *(half4*)(vT + ((size_t)bb * D_ + d) * SE + s0 + sq * 4) = o;
        }
    }
    __syncthreads();

    // phase 4: k' C-frags -> bs (overwrite), then coalesced row-major writeout
    #pragma unroll
    for (int nt = 0; nt < 8; ++nt)
        #pragma unroll
        for (int r = 0; r < 4; ++r)
            bs[(wave * 16 + quad * 4 + r) * LDB + nt * 16 + l15] = (_Float16)acc[nt][r];
    __syncthreads();
    _Float16* kg = kp + ((size_t)bb * SE + s0) * D_;
    {
        const int row = tid >> 2;
        #pragma unroll
        for (int it = 0; it < 4; ++it) {
            int ch = (tid & 3) + it * 4;
            half8 v = *(const half8*)(bs + row * LDB + ch * 8);
            *(half8*)(kg + row * D_ + ch * 8) = v;
        }
    }
}

// ---------- fused flash attention: 512 threads, waves = 2 wq x 4 ws ----------
// Each wave: 32 q rows (2 subtiles) x a 16-s slice -> 8 KB LDS frag reads per
// tile for 2x the MFMA work (K and V frags reused across the 2 q-subtiles).
// Same NT=64 K/V images / XOR swizzles / DMA as verified rounds 7/9.
// Exact 4-way s-split merge in a 2-phase epilogue.
__global__ __launch_bounds__(512, 4) void flash(const float* __restrict__ h,
                                                const _Float16* __restrict__ k,
                                                const _Float16* __restrict__ vT,
                                                float* __restrict__ out) {
    __shared__ _Float16 KV[2][16384];        // per buf: K image 8192 halves + V image 8192
    __shared__ float mlbuf[2][4][16][2];     // [wq][ws][q16][m,l]  (ws0 slots unused)

    const int bb   = blockIdx.y;
    const int q0   = blockIdx.x * 64;
    const int tid  = threadIdx.x;      // 0..511
    const int wave = tid >> 6;         // 0..7
    const int wq   = wave >> 2;        // q-group 0..1 (32 q rows each)
    const int ws   = wave & 3;         // s-group 0..3 (16 s each per tile)
    const int lane = tid & 63;
    const int l15  = lane & 15;
    const int quad = lane >> 4;

    const _Float16* kbase = k + (size_t)bb * SE * D_;
    const _Float16* vbase = vT + (size_t)bb * D_ * SE;

    // per-lane DMA gather offsets (verified formulas); 1024 chunks/image, 2 rounds
    int koff[2], voff[2];
    #pragma unroll
    for (int it = 0; it < 2; ++it) {
        int i = it * 512 + wave * 64 + lane;      // linear 16B chunk index in image
        int kr = i >> 4, kpp = i & 15;            // K: 64 rows x 16 chunks
        koff[it] = kr * D_ + (kpp ^ (kr & 15)) * 8;
        int vr = i >> 3, vpp = i & 7;             // V: 128 rows x 8 chunks
        voff[it] = vr * SE + (vpp ^ (vr & 7)) * 8;
    }

    // hoisted LDS read bases. K row = ws*16 + l15 (row&15 == l15 -> same swizzle);
    // V chunk c = 2*ws + (quad>>1), stored at c^(row&7), row&7 == l15&7.
    const _Float16* kA0[4]; const _Float16* kA1[4];
    const _Float16* vB0;    const _Float16* vB1;
    #pragma unroll
    for (int ks = 0; ks < 4; ++ks) {
        int o = (ws * 16 + l15) * 128 + (((ks * 4 + quad) ^ l15) * 8);
        kA0[ks] = &KV[0][o]; kA1[ks] = &KV[1][o];
    }
    {
        int o = 8192 + l15 * 64 + (((2 * ws + (quad >> 1)) ^ (l15 & 7)) * 8) + (quad & 1) * 4;
        vB0 = &KV[0][o]; vB1 = &KV[1][o];
    }

    // issue tile 0 DMA
    {
        _Float16* buf0 = &KV[0][0];
        #pragma unroll
        for (int it = 0; it < 2; ++it) {
            cp16_async(kbase + koff[it], buf0 + (it * 512 + wave * 64) * 8);
            cp16_async(vbase + voff[it], buf0 + 8192 + (it * 512 + wave * 64) * 8);
        }
    }

    // Q = fp16(h * log2e) B-fragments for the wave's two q-subtiles
    half8 qf[2][4];
    #pragma unroll
    for (int qt = 0; qt < 2; ++qt) {
        const float* hrow = h + ((size_t)bb * SD + q0 + wq * 32 + qt * 16 + l15) * D_;
        #pragma unroll
        for (int ks = 0; ks < 4; ++ks) {
            float4 a = *(const float4*)(hrow + ks * 32 + quad * 8);
            float4 c = *(const float4*)(hrow + ks * 32 + quad * 8 + 4);
            half8 f;
            f[0] = (_Float16)(a.x * LOG2E); f[1] = (_Float16)(a.y * LOG2E);
            f[2] = (_Float16)(a.z * LOG2E); f[3] = (_Float16)(a.w * LOG2E);
            f[4] = (_Float16)(c.x * LOG2E); f[5] = (_Float16)(c.y * LOG2E);
            f[6] = (_Float16)(c.z * LOG2E); f[7] = (_Float16)(c.w * LOG2E);
            qf[qt][ks] = f;
        }
    }

    floatx4 acc_o[2][8];
    #pragma unroll
    for (int qt = 0; qt < 2; ++qt)
        #pragma unroll
        for (int dt = 0; dt < 8; ++dt) acc_o[qt][dt] = (floatx4){0.f, 0.f, 0.f, 0.f};
    float m_q[2] = {-1e30f, -1e30f};
    float l_part[2] = {0.f, 0.f};
    const half2v one2 = { (_Float16)1.f, (_Float16)1.f };

    for (int t = 0; t < SE / NT; ++t) {
        __syncthreads();   // vmcnt drain -> tile t landed for all waves
        if (t + 1 < SE / NT) {
            const _Float16* kt = kbase + (size_t)(t + 1) * (NT * D_);
            const _Float16* vt = vbase + (size_t)(t + 1) * NT;
            _Float16* bufn = &KV[(t + 1) & 1][0];
            #pragma unroll
            for (int it = 0; it < 2; ++it) {
                cp16_async(kt + koff[it], bufn + (it * 512 + wave * 64) * 8);
                cp16_async(vt + voff[it], bufn + 8192 + (it * 512 + wave * 64) * 8);
            }
        }
        const bool odd = (t & 1) != 0;
        const _Float16* vB = odd ? vB1 : vB0;

        // S^T = K Q^T on this wave's 16-s slice: C row s=quad*4+r, col q=l15
        floatx4 accs[2];
        accs[0] = (floatx4){0.f, 0.f, 0.f, 0.f};
        accs[1] = (floatx4){0.f, 0.f, 0.f, 0.f};
        #pragma unroll
        for (int ks = 0; ks < 4; ++ks) {
            half8 af = *(const half8*)(odd ? kA1[ks] : kA0[ks]);
            accs[0] = __builtin_amdgcn_mfma_f32_16x16x32_f16(af, qf[0][ks], accs[0], 0, 0, 0);
            accs[1] = __builtin_amdgcn_mfma_f32_16x16x32_f16(af, qf[1][ks], accs[1], 0, 0, 0);
        }

        // deferred-rescale online softmax, base-2 (fast path: no cross-lane ops)
        float mv[2];
        #pragma unroll
        for (int qt = 0; qt < 2; ++qt)
            mv[qt] = fmaxf(fmaxf(accs[qt][0], accs[qt][1]), fmaxf(accs[qt][2], accs[qt][3]));
        bool cond = (mv[0] > m_q[0] + 11.5f) || (mv[1] > m_q[1] + 11.5f);
        if (__ballot(cond) != 0ull) {   // rare wave-uniform slow path
            #pragma unroll
            for (int qt = 0; qt < 2; ++qt) {
                float m = mv[qt];
                m = fmaxf(m, __shfl_xor(m, 16, 64));
                m = fmaxf(m, __shfl_xor(m, 32, 64));
                float mnew = fmaxf(m_q[qt], m);
                float alpha = exp2f(m_q[qt] - mnew);
                l_part[qt] *= alpha;
                float ab[4];
                #pragma unroll
                for (int r = 0; r < 4; ++r) ab[r] = __shfl(alpha, quad * 4 + r, 64);
                #pragma unroll
                for (int dt = 0; dt < 8; ++dt)
                    #pragma unroll
                    for (int r = 0; r < 4; ++r) acc_o[qt][dt][r] *= ab[r];
                m_q[qt] = mnew;
            }
        }

        // P = 2^(S^T - m); pf[qt] IS the PV A-fragment (m=q=l15, k=s=quad*4+r)
        half4 pf[2];
        #pragma unroll
        for (int qt = 0; qt < 2; ++qt) {
            float p0 = exp2f(accs[qt][0] - m_q[qt]);
            float p1 = exp2f(accs[qt][1] - m_q[qt]);
            float p2 = exp2f(accs[qt][2] - m_q[qt]);
            float p3 = exp2f(accs[qt][3] - m_q[qt]);
            half2v lo = __builtin_bit_cast(half2v, __builtin_amdgcn_cvt_pkrtz(p0, p1));
            half2v hi = __builtin_bit_cast(half2v, __builtin_amdgcn_cvt_pkrtz(p2, p3));
#if __has_builtin(__builtin_amdgcn_fdot2)
            l_part[qt] = __builtin_amdgcn_fdot2(lo, one2, l_part[qt], false);
            l_part[qt] = __builtin_amdgcn_fdot2(hi, one2, l_part[qt], false);
#else
            l_part[qt] += p0 + p1 + p2 + p3;
#endif
            half4 pv; pv[0] = lo[0]; pv[1] = lo[1]; pv[2] = hi[0]; pv[3] = hi[1];
            pf[qt] = pv;
        }

        // O += P V : V frag read once per dt, shared across the 2 q-subtiles
        #pragma unroll
        for (int dt = 0; dt < 8; ++dt) {
            half4 vf = *(const half4*)(vB + dt * 1024);
            acc_o[0][dt] = __builtin_amdgcn_mfma_f32_16x16x16f16(pf[0], vf, acc_o[0][dt], 0, 0, 0);
            acc_o[1][dt] = __builtin_amdgcn_mfma_f32_16x16x16f16(pf[1], vf, acc_o[1][dt], 0, 0, 0);
        }
    }

    // ---- epilogue: exact 4-way s-split merge, 2 phases (one per q-subtile) ----
    float l_own[2];
    #pragma unroll
    for (int qt = 0; qt < 2; ++qt) {
        float l = l_part[qt];
        l += __shfl_xor(l, 16, 64);
        l += __shfl_xor(l, 32, 64);
        l_own[qt] = l;                 // denominator partial for q = l15
    }

    float* Ob = (float*)&KV[0][0];     // 6 regions x 2048 floats (8 KB) = 48 KB

    #pragma unroll
    for (int qt = 0; qt < 2; ++qt) {
        __syncthreads();               // (qt=0: PV reads done) / (qt=1: phase-0 reads done)
        if (ws != 0) {
            float* reg = Ob + (wq * 3 + (ws - 1)) * 2048;
            #pragma unroll
            for (int dt = 0; dt < 8; ++dt)
                *(floatx4*)(reg + (dt * 64 + lane) * 4) = acc_o[qt][dt];
            if (quad == 0) {
                mlbuf[wq][ws][l15][0] = m_q[qt];
                mlbuf[wq][ws][l15][1] = l_own[qt];
            }
        }
        __syncthreads();
        if (ws == 0) {
            float m0 = m_q[qt],           l0 = l_own[qt];
            float m1 = mlbuf[wq][1][l15][0], l1 = mlbuf[wq][1][l15][1];
            float m2 = mlbuf[wq][2][l15][0], l2 = mlbuf[wq][2][l15][1];
            float m3 = mlbuf[wq][3][l15][0], l3 = mlbuf[wq][3][l15][1];
            float mm = fmaxf(fmaxf(m0, m1), fmaxf(m2, m3));
            float a0 = exp2f(m0 - mm), a1 = exp2f(m1 - mm);
            float a2 = exp2f(m2 - mm), a3 = exp2f(m3 - mm);
            float linv = 1.f / (l0 * a0 + l1 * a1 + l2 * a2 + l3 * a3);
            float a0b[4], a1b[4], a2b[4], a3b[4], lb[4];
            #pragma unroll
            for (int r = 0; r < 4; ++r) {
                int src = quad * 4 + r;
                a0b[r] = __shfl(a0, src, 64);
                a1b[r] = __shfl(a1, src, 64);
                a2b[r] = __shfl(a2, src, 64);
                a3b[r] = __shfl(a3, src, 64);
                lb[r]  = __shfl(linv, src, 64);
            }
            float* orow = out + ((size_t)bb * SD + q0 + wq * 32 + qt * 16 + quad * 4) * D_;
            #pragma unroll
            for (int dt = 0; dt < 8; ++dt) {
                floatx4 o1 = *(floatx4*)(Ob + (wq * 3 + 0) * 2048 + (dt * 64 + lane) * 4);
                floatx4 o2 = *(floatx4*)(Ob + (wq * 3 + 1) * 2048 + (dt * 64 + lane) * 4);
                floatx4 o3 = *(floatx4*)(Ob + (wq * 3 + 2) * 2048 + (dt * 64 + lane) * 4);
                #pragma unroll
                for (int r = 0; r < 4; ++r)
                    orow[(size_t)r * D_ + dt * 16 + l15] =
                        (acc_o[qt][dt][r] * a0b[r] + o1[r] * a1b[r]
                         + o2[r] * a2b[r] + o3[r] * a3b[r]) * lb[r];
            }
        }
    }
}

extern "C" void kernel_launch(void* const* d_in, const int* in_sizes, int n_in,
                              void* d_out, int out_size, void* d_ws, size_t ws_size,
                              hipStream_t stream) {
    const float* b = (const float*)d_in[0];   // [B, SE, D]
    const float* h = (const float*)d_in[1];   // [B, SD, D]
    const float* W = (const float*)d_in[2];   // [D, D]
    float* out = (float*)d_out;               // [B, SD, D] fp32

    _Float16* W16 = (_Float16*)d_ws;                       // 32 KB
    _Float16* Wlo = W16 + 128 * 128;                       // 32 KB
    _Float16* kp  = Wlo + 128 * 128;                       // [B, SE, D] fp16
    _Float16* vT  = kp + (size_t)B_ * SE * D_;             // [B, D, SE] fp16

    wprep<<<64, 256, 0, stream>>>(W, W16, Wlo);
    kvprep<<<dim3(SE / 64, B_), 256, 0, stream>>>(b, W16, Wlo, kp, vT);
    flash<<<dim3(SD / 64, B_), 512, 0, stream>>>(h, kp, vT, out);
}